// Round 2
// baseline (147.724 us; speedup 1.0000x reference)
//
#include <hip/hip_runtime.h>
#include <hip/hip_bf16.h>

typedef __attribute__((ext_vector_type(8))) short short8;
typedef __attribute__((ext_vector_type(4))) float f32x4;

#define DDIM 256

static __device__ __forceinline__ unsigned short f2bf(float f){
  unsigned b = __builtin_bit_cast(unsigned, f);
  b += 0x7FFFu + ((b >> 16) & 1u);          // RNE round to bf16
  return (unsigned short)(b >> 16);
}

// ---------------------------------------------------------------------------
// Kernel A: build Q = H_{U[255]} ... H_{U[0]} column-by-column.
// One wave handles 2 columns (independent sequential chains of 256 steps).
// Writes Q^T (bf16) to ws: Qt[n][k] = Q[k][n], row-major 256x256.
// ---------------------------------------------------------------------------
__global__ __launch_bounds__(256) void compute_q(const float* __restrict__ U,
                                                 unsigned short* __restrict__ Qt){
  const int lane = threadIdx.x & 63;
  const int wv   = threadIdx.x >> 6;          // 0..3
  const int pair = blockIdx.x * 4 + wv;       // 0..127
  const int j0 = pair * 2, j1 = j0 + 1;

  float u0[4], u1[4], v[4];
#pragma unroll
  for (int e = 0; e < 4; ++e){
    const int i = e * 64 + lane;
    u0[e] = (i == j0) ? 1.f : 0.f;
    u1[e] = (i == j1) ? 1.f : 0.f;
    v[e]  = U[i];                             // prefetch row k=0
  }

  for (int k = 0; k < 256; ++k){
    float nv[4];
    const int kn = (k + 1) & 255;             // wrap: last prefetch unused
#pragma unroll
    for (int e = 0; e < 4; ++e) nv[e] = U[kn * 256 + e * 64 + lane];

    float d0 = 0.f, d1 = 0.f, dv = 0.f;
#pragma unroll
    for (int e = 0; e < 4; ++e){
      d0 += u0[e] * v[e];
      d1 += u1[e] * v[e];
      dv += v[e] * v[e];
    }
#pragma unroll
    for (int off = 32; off > 0; off >>= 1){
      d0 += __shfl_xor(d0, off, 64);
      d1 += __shfl_xor(d1, off, 64);
      dv += __shfl_xor(dv, off, 64);
    }
    const float inv = 2.0f / dv;
    const float c0 = d0 * inv, c1 = d1 * inv;
#pragma unroll
    for (int e = 0; e < 4; ++e){
      u0[e] = fmaf(-c0, v[e], u0[e]);
      u1[e] = fmaf(-c1, v[e], u1[e]);
      v[e]  = nv[e];
    }
  }

#pragma unroll
  for (int e = 0; e < 4; ++e){
    const int i = e * 64 + lane;
    Qt[(size_t)j0 * 256 + i] = f2bf(u0[e]);
    Qt[(size_t)j1 * 256 + i] = f2bf(u1[e]);
  }
}

// ---------------------------------------------------------------------------
// Kernel B: Y = X * Q.  Block = 128 rows x 256 cols (full N).
// 8 waves, wave w owns rows w*16..w*16+15.  Q^T staged once into 128 KB LDS
// (XOR-swizzled: byte ^= (n&7)<<4 within each 512B row) for conflict-uniform
// ds_read_b128.  A loaded fp32 global->reg, converted to bf16 fragments.
// mfma_f32_16x16x32_bf16 layouts (m89/m97):
//   A: lane holds A[l&15][8*(l>>4)+j]   B: lane holds B[8*(l>>4)+j][l&15]
//   D: D[(l>>4)*4+r][l&15]
// ---------------------------------------------------------------------------
__global__ __launch_bounds__(512) void gemm_xq(const float* __restrict__ X,
                                               const unsigned short* __restrict__ Qt,
                                               float* __restrict__ Y){
  __shared__ char qb[131072];                 // 256 rows (n) x 512 B (k, bf16)

  const int tid  = threadIdx.x;
  const int lane = tid & 63;
  const int wv   = tid >> 6;                  // 0..7
  const int lg   = lane >> 4;                 // 0..3
  const int lm   = lane & 15;

  // Issue A loads first (latency overlap with Q staging).
  const size_t grow = (size_t)blockIdx.x * 128 + wv * 16 + lm;
  const float* xp = X + grow * DDIM + lg * 8;
  f32x4 av[16];
#pragma unroll
  for (int kk = 0; kk < 8; ++kk){
    av[2*kk]   = *reinterpret_cast<const f32x4*>(xp + kk * 32);
    av[2*kk+1] = *reinterpret_cast<const f32x4*>(xp + kk * 32 + 4);
  }

  // Stage Q^T -> LDS. 8192 16B chunks, 16 per thread, coalesced reads.
#pragma unroll
  for (int it = 0; it < 16; ++it){
    const int c   = tid + it * 512;           // 0..8191
    const int n   = c >> 5;                   // row (n-dim)
    const int off = (c & 31) << 4;            // byte offset within row
    const f32x4 d = *reinterpret_cast<const f32x4*>(
        reinterpret_cast<const char*>(Qt) + (n << 9) + off);
    *reinterpret_cast<f32x4*>(qb + (n << 9) + (off ^ ((n & 7) << 4))) = d;
  }
  __syncthreads();

  f32x4 acc[16];
#pragma unroll
  for (int nt = 0; nt < 16; ++nt) acc[nt] = (f32x4){0.f, 0.f, 0.f, 0.f};

#pragma unroll
  for (int kk = 0; kk < 8; ++kk){
    // Convert this k-chunk of A to a bf16 fragment (8 consecutive k).
    const f32x4 lo = av[2*kk], hi = av[2*kk+1];
    short8 a;
    a[0] = (short)f2bf(lo[0]); a[1] = (short)f2bf(lo[1]);
    a[2] = (short)f2bf(lo[2]); a[3] = (short)f2bf(lo[3]);
    a[4] = (short)f2bf(hi[0]); a[5] = (short)f2bf(hi[1]);
    a[6] = (short)f2bf(hi[2]); a[7] = (short)f2bf(hi[3]);

    const int kb = kk * 64 + (lg << 4);       // byte offset of lane's 8 bf16 in k
#pragma unroll
    for (int nt = 0; nt < 16; ++nt){
      const int n = nt * 16 + lm;
      const short8 b = *reinterpret_cast<const short8*>(
          qb + (n << 9) + (kb ^ ((n & 7) << 4)));
      acc[nt] = __builtin_amdgcn_mfma_f32_16x16x32_bf16(a, b, acc[nt], 0, 0, 0);
    }
  }

  // Epilogue: D[(l>>4)*4+r][l&15] per 16x16 tile.
  const size_t orow = (size_t)blockIdx.x * 128 + wv * 16 + lg * 4;
#pragma unroll
  for (int nt = 0; nt < 16; ++nt){
#pragma unroll
    for (int r = 0; r < 4; ++r){
      Y[(orow + r) * DDIM + nt * 16 + lm] = acc[nt][r];
    }
  }
}

extern "C" void kernel_launch(void* const* d_in, const int* in_sizes, int n_in,
                              void* d_out, int out_size, void* d_ws, size_t ws_size,
                              hipStream_t stream) {
  const float* X = (const float*)d_in[0];     // [131072, 256]
  const float* U = (const float*)d_in[1];     // [256, 256]
  float* Y = (float*)d_out;                   // [131072, 256]
  unsigned short* Qt = (unsigned short*)d_ws; // 256*256 bf16 = 128 KB scratch

  compute_q<<<32, 256, 0, stream>>>(U, Qt);
  gemm_xq<<<131072 / 128, 512, 0, stream>>>(X, Qt, Y);
}

// Round 3
// 139.630 us; speedup vs baseline: 1.0580x; 1.0580x over previous
//
#include <hip/hip_runtime.h>
#include <hip/hip_bf16.h>

typedef __attribute__((ext_vector_type(8))) short short8;
typedef __attribute__((ext_vector_type(4))) float f32x4;

#define DDIM 256

static __device__ __forceinline__ unsigned short f2bf(float f){
  unsigned b = __builtin_bit_cast(unsigned, f);
  b += 0x7FFFu + ((b >> 16) & 1u);          // RNE round to bf16
  return (unsigned short)(b >> 16);
}

// Wave64 sum-reduction via DPP (VALU-only, ~40 cy chain vs ~720 cy for
// ds_bpermute-based __shfl_xor). row_shr 1/2/4/8 -> row sums in lanes
// 15/31/47/63; BCAST15+BCAST31 accumulate rows -> total in lane 63;
// v_readlane broadcasts to all lanes via SGPR.
static __device__ __forceinline__ float wave_sum_bcast(float x){
  int v = __builtin_bit_cast(int, x);
#define DPP_ADD(ctrl)                                                          \
  v = __builtin_bit_cast(int,                                                  \
        __builtin_bit_cast(float, v) +                                         \
        __builtin_bit_cast(float,                                              \
          __builtin_amdgcn_update_dpp(0, v, (ctrl), 0xF, 0xF, true)))
  DPP_ADD(0x111);  // row_shr:1
  DPP_ADD(0x112);  // row_shr:2
  DPP_ADD(0x114);  // row_shr:4
  DPP_ADD(0x118);  // row_shr:8
  DPP_ADD(0x142);  // row_bcast:15
  DPP_ADD(0x143);  // row_bcast:31
#undef DPP_ADD
  return __builtin_bit_cast(float, __builtin_amdgcn_readlane(v, 63));
}

// ---------------------------------------------------------------------------
// Kernel 0: beta[k] = 2 / ||U[k]||^2  (removes divide + one reduce from the
// 256-step critical chain in compute_q).
// ---------------------------------------------------------------------------
__global__ __launch_bounds__(256) void compute_beta(const float* __restrict__ U,
                                                    float* __restrict__ beta){
  const int k = threadIdx.x;
  const f32x4* r = reinterpret_cast<const f32x4*>(U + (size_t)k * 256);
  float s0 = 0.f, s1 = 0.f, s2 = 0.f, s3 = 0.f;
#pragma unroll
  for (int i = 0; i < 64; i += 4){
    f32x4 a = r[i], b = r[i + 1], c = r[i + 2], d = r[i + 3];
    s0 += a[0]*a[0] + a[1]*a[1] + a[2]*a[2] + a[3]*a[3];
    s1 += b[0]*b[0] + b[1]*b[1] + b[2]*b[2] + b[3]*b[3];
    s2 += c[0]*c[0] + c[1]*c[1] + c[2]*c[2] + c[3]*c[3];
    s3 += d[0]*d[0] + d[1]*d[1] + d[2]*d[2] + d[3]*d[3];
  }
  beta[k] = 2.0f / ((s0 + s1) + (s2 + s3));
}

// ---------------------------------------------------------------------------
// Kernel A: build Q = H_{U[255]} ... H_{U[0]} column-by-column.
// One wave handles 2 columns (independent sequential chains of 256 steps).
// Writes Q^T (bf16) to ws: Qt[n][k] = Q[k][n], row-major 256x256.
// ---------------------------------------------------------------------------
__global__ __launch_bounds__(256) void compute_q(const float* __restrict__ U,
                                                 const float* __restrict__ beta,
                                                 unsigned short* __restrict__ Qt){
  const int lane = threadIdx.x & 63;
  const int wv   = threadIdx.x >> 6;          // 0..3
  const int pair = blockIdx.x * 4 + wv;       // 0..127
  const int j0 = pair * 2, j1 = j0 + 1;

  float u0[4], u1[4], v[4];
#pragma unroll
  for (int e = 0; e < 4; ++e){
    const int i = e * 64 + lane;
    u0[e] = (i == j0) ? 1.f : 0.f;
    u1[e] = (i == j1) ? 1.f : 0.f;
    v[e]  = U[i];                             // prefetch row k=0
  }
  float b = beta[0];

  for (int k = 0; k < 256; ++k){
    float nv[4];
    const int kn = (k + 1) & 255;             // wrap: last prefetch unused
#pragma unroll
    for (int e = 0; e < 4; ++e) nv[e] = U[kn * 256 + e * 64 + lane];
    const float nb = beta[kn];

    const float p0 = (u0[0]*v[0] + u0[1]*v[1]) + (u0[2]*v[2] + u0[3]*v[3]);
    const float p1 = (u1[0]*v[0] + u1[1]*v[1]) + (u1[2]*v[2] + u1[3]*v[3]);
    const float d0 = wave_sum_bcast(p0);
    const float d1 = wave_sum_bcast(p1);

    const float c0 = d0 * b, c1 = d1 * b;
#pragma unroll
    for (int e = 0; e < 4; ++e){
      u0[e] = fmaf(-c0, v[e], u0[e]);
      u1[e] = fmaf(-c1, v[e], u1[e]);
      v[e]  = nv[e];
    }
    b = nb;
  }

#pragma unroll
  for (int e = 0; e < 4; ++e){
    const int i = e * 64 + lane;
    Qt[(size_t)j0 * 256 + i] = f2bf(u0[e]);
    Qt[(size_t)j1 * 256 + i] = f2bf(u1[e]);
  }
}

// ---------------------------------------------------------------------------
// Kernel B: Y = X * Q.  Block = 128 rows x 256 cols (full N).
// 8 waves, wave w owns rows w*16..w*16+15.  Q^T staged once into 128 KB LDS
// (XOR-swizzled: byte ^= (n&7)<<4 within each 512B row) for conflict-uniform
// ds_read_b128.  A loaded fp32 global->reg, converted to bf16 fragments.
// mfma_f32_16x16x32_bf16 layouts (m89/m97):
//   A: lane holds A[l&15][8*(l>>4)+j]   B: lane holds B[8*(l>>4)+j][l&15]
//   D: D[(l>>4)*4+r][l&15]
// ---------------------------------------------------------------------------
__global__ __launch_bounds__(512) void gemm_xq(const float* __restrict__ X,
                                               const unsigned short* __restrict__ Qt,
                                               float* __restrict__ Y){
  __shared__ char qb[131072];                 // 256 rows (n) x 512 B (k, bf16)

  const int tid  = threadIdx.x;
  const int lane = tid & 63;
  const int wv   = tid >> 6;                  // 0..7
  const int lg   = lane >> 4;                 // 0..3
  const int lm   = lane & 15;

  // Issue A loads first (latency overlap with Q staging).
  const size_t grow = (size_t)blockIdx.x * 128 + wv * 16 + lm;
  const float* xp = X + grow * DDIM + lg * 8;
  f32x4 av[16];
#pragma unroll
  for (int kk = 0; kk < 8; ++kk){
    av[2*kk]   = *reinterpret_cast<const f32x4*>(xp + kk * 32);
    av[2*kk+1] = *reinterpret_cast<const f32x4*>(xp + kk * 32 + 4);
  }

  // Stage Q^T -> LDS. 8192 16B chunks, 16 per thread, coalesced reads.
#pragma unroll
  for (int it = 0; it < 16; ++it){
    const int c   = tid + it * 512;           // 0..8191
    const int n   = c >> 5;                   // row (n-dim)
    const int off = (c & 31) << 4;            // byte offset within row
    const f32x4 d = *reinterpret_cast<const f32x4*>(
        reinterpret_cast<const char*>(Qt) + (n << 9) + off);
    *reinterpret_cast<f32x4*>(qb + (n << 9) + (off ^ ((n & 7) << 4))) = d;
  }
  __syncthreads();

  f32x4 acc[16];
#pragma unroll
  for (int nt = 0; nt < 16; ++nt) acc[nt] = (f32x4){0.f, 0.f, 0.f, 0.f};

#pragma unroll
  for (int kk = 0; kk < 8; ++kk){
    // Convert this k-chunk of A to a bf16 fragment (8 consecutive k).
    const f32x4 lo = av[2*kk], hi = av[2*kk+1];
    short8 a;
    a[0] = (short)f2bf(lo[0]); a[1] = (short)f2bf(lo[1]);
    a[2] = (short)f2bf(lo[2]); a[3] = (short)f2bf(lo[3]);
    a[4] = (short)f2bf(hi[0]); a[5] = (short)f2bf(hi[1]);
    a[6] = (short)f2bf(hi[2]); a[7] = (short)f2bf(hi[3]);

    const int kb = kk * 64 + (lg << 4);       // byte offset of lane's 8 bf16 in k
#pragma unroll
    for (int nt = 0; nt < 16; ++nt){
      const int n = nt * 16 + lm;
      const short8 b = *reinterpret_cast<const short8*>(
          qb + (n << 9) + (kb ^ ((n & 7) << 4)));
      acc[nt] = __builtin_amdgcn_mfma_f32_16x16x32_bf16(a, b, acc[nt], 0, 0, 0);
    }
  }

  // Epilogue: D[(l>>4)*4+r][l&15] per 16x16 tile.
  const size_t orow = (size_t)blockIdx.x * 128 + wv * 16 + lg * 4;
#pragma unroll
  for (int nt = 0; nt < 16; ++nt){
#pragma unroll
    for (int r = 0; r < 4; ++r){
      Y[(orow + r) * DDIM + nt * 16 + lm] = acc[nt][r];
    }
  }
}

extern "C" void kernel_launch(void* const* d_in, const int* in_sizes, int n_in,
                              void* d_out, int out_size, void* d_ws, size_t ws_size,
                              hipStream_t stream) {
  const float* X = (const float*)d_in[0];     // [131072, 256]
  const float* U = (const float*)d_in[1];     // [256, 256]
  float* Y = (float*)d_out;                   // [131072, 256]
  unsigned short* Qt = (unsigned short*)d_ws; // 256*256 bf16 = 128 KB scratch

  // beta lives in the tail of d_out: consumed by compute_q (stream-ordered)
  // before gemm_xq overwrites all of d_out.
  float* beta = (float*)d_out + ((size_t)out_size - 256);

  compute_beta<<<1, 256, 0, stream>>>(U, beta);
  compute_q<<<32, 256, 0, stream>>>(U, beta, Qt);
  gemm_xq<<<131072 / 128, 512, 0, stream>>>(X, Qt, Y);
}

// Round 4
// 112.486 us; speedup vs baseline: 1.3133x; 1.2413x over previous
//
#include <hip/hip_runtime.h>
#include <hip/hip_bf16.h>

typedef __attribute__((ext_vector_type(8))) short short8;
typedef __attribute__((ext_vector_type(4))) float f32x4;

#define DDIM 256
#define NROWS 131072
#define GBLK 256              // persistent blocks (1 per CU)
#define RPB (NROWS / GBLK)    // 512 rows per block
#define CHUNK 128             // rows per pipeline chunk
                              // NCHUNK = 4

static __device__ __forceinline__ unsigned short f2bf(float f){
  unsigned b = __builtin_bit_cast(unsigned, f);
  b += 0x7FFFu + ((b >> 16) & 1u);          // RNE round to bf16
  return (unsigned short)(b >> 16);
}

// Wave64 sum-reduction via DPP (VALU-only). row_shr 1/2/4/8 then
// row_bcast:15 / row_bcast:31 -> total in lane 63; readlane broadcasts.
static __device__ __forceinline__ float wave_sum_bcast(float x){
  int v = __builtin_bit_cast(int, x);
#define DPP_ADD(ctrl)                                                          \
  v = __builtin_bit_cast(int,                                                  \
        __builtin_bit_cast(float, v) +                                         \
        __builtin_bit_cast(float,                                              \
          __builtin_amdgcn_update_dpp(0, v, (ctrl), 0xF, 0xF, true)))
  DPP_ADD(0x111);  // row_shr:1
  DPP_ADD(0x112);  // row_shr:2
  DPP_ADD(0x114);  // row_shr:4
  DPP_ADD(0x118);  // row_shr:8
  DPP_ADD(0x142);  // row_bcast:15
  DPP_ADD(0x143);  // row_bcast:31
#undef DPP_ADD
  return __builtin_bit_cast(float, __builtin_amdgcn_readlane(v, 63));
}

// ---------------------------------------------------------------------------
// Kernel 0: beta[k] = 2 / ||U[k]||^2.
// ---------------------------------------------------------------------------
__global__ __launch_bounds__(256) void compute_beta(const float* __restrict__ U,
                                                    float* __restrict__ beta){
  const int k = threadIdx.x;
  const f32x4* r = reinterpret_cast<const f32x4*>(U + (size_t)k * 256);
  float s0 = 0.f, s1 = 0.f, s2 = 0.f, s3 = 0.f;
#pragma unroll
  for (int i = 0; i < 64; i += 4){
    f32x4 a = r[i], b = r[i + 1], c = r[i + 2], d = r[i + 3];
    s0 += a[0]*a[0] + a[1]*a[1] + a[2]*a[2] + a[3]*a[3];
    s1 += b[0]*b[0] + b[1]*b[1] + b[2]*b[2] + b[3]*b[3];
    s2 += c[0]*c[0] + c[1]*c[1] + c[2]*c[2] + c[3]*c[3];
    s3 += d[0]*d[0] + d[1]*d[1] + d[2]*d[2] + d[3]*d[3];
  }
  beta[k] = 2.0f / ((s0 + s1) + (s2 + s3));
}

// ---------------------------------------------------------------------------
// Kernel A: Q columns via 256 sequential Householder steps; 2 cols/wave.
// Depth-4 rotating prefetch of U rows + betas hides ~250cy L2 latency under
// 4 x ~70cy step bodies.  Writes Q^T (bf16) to Qt[n][k].
// ---------------------------------------------------------------------------
__global__ __launch_bounds__(256) void compute_q(const float* __restrict__ U,
                                                 const float* __restrict__ beta,
                                                 unsigned short* __restrict__ Qt){
  const int lane = threadIdx.x & 63;
  const int wv   = threadIdx.x >> 6;          // 0..3
  const int pair = blockIdx.x * 4 + wv;       // 0..127
  const int j0 = pair * 2, j1 = j0 + 1;

  float u0[4], u1[4], r0[4], r1[4], r2[4], r3[4];
#pragma unroll
  for (int e = 0; e < 4; ++e){
    const int i = e * 64 + lane;
    u0[e] = (i == j0) ? 1.f : 0.f;
    u1[e] = (i == j1) ? 1.f : 0.f;
    r0[e] = U[0 * 256 + i];
    r1[e] = U[1 * 256 + i];
    r2[e] = U[2 * 256 + i];
    r3[e] = U[3 * 256 + i];
  }
  float b0 = beta[0], b1 = beta[1], b2 = beta[2], b3 = beta[3];

#define QSTEP(R, B, KN)                                                        \
  do {                                                                         \
    const float p0_ = (u0[0]*R[0] + u0[1]*R[1]) + (u0[2]*R[2] + u0[3]*R[3]);   \
    const float p1_ = (u1[0]*R[0] + u1[1]*R[1]) + (u1[2]*R[2] + u1[3]*R[3]);   \
    const float d0_ = wave_sum_bcast(p0_);                                     \
    const float d1_ = wave_sum_bcast(p1_);                                     \
    const float c0_ = d0_ * B, c1_ = d1_ * B;                                  \
    _Pragma("unroll")                                                          \
    for (int e = 0; e < 4; ++e){                                               \
      u0[e] = fmaf(-c0_, R[e], u0[e]);                                         \
      u1[e] = fmaf(-c1_, R[e], u1[e]);                                         \
      R[e] = U[(size_t)(KN) * 256 + e * 64 + lane];                            \
    }                                                                          \
    B = beta[(KN)];                                                            \
  } while (0)

  for (int k = 0; k < 256; k += 4){
    const int k4 = (k+4) & 255, k5 = (k+5) & 255, k6 = (k+6) & 255, k7 = (k+7) & 255;
    QSTEP(r0, b0, k4);
    QSTEP(r1, b1, k5);
    QSTEP(r2, b2, k6);
    QSTEP(r3, b3, k7);
  }
#undef QSTEP

#pragma unroll
  for (int e = 0; e < 4; ++e){
    const int i = e * 64 + lane;
    Qt[(size_t)j0 * 256 + i] = f2bf(u0[e]);
    Qt[(size_t)j1 * 256 + i] = f2bf(u1[e]);
  }
}

// ---------------------------------------------------------------------------
// Kernel B: Y = X * Q, persistent.  256 blocks x 512 threads; block owns 512
// rows; Qt staged into LDS ONCE (XOR-swizzled), one barrier, then 4 chunks of
// 128 rows with double-buffered X register prefetch and no further barriers.
// mfma_f32_16x16x32_bf16 layouts (m89/m97):
//   A: lane holds A[l&15][8*(l>>4)+j]   B: lane holds B[8*(l>>4)+j][l&15]
//   D: D[(l>>4)*4+r][l&15]
// ---------------------------------------------------------------------------
__global__ __launch_bounds__(512, 2) void gemm_xq(const float* __restrict__ X,
                                                  const unsigned short* __restrict__ Qt,
                                                  float* __restrict__ Y){
  __shared__ char qb[131072];                 // 256 rows (n) x 512 B (k, bf16)

  const int tid  = threadIdx.x;
  const int lane = tid & 63;
  const int wv   = tid >> 6;                  // 0..7
  const int lg   = lane >> 4;                 // 0..3
  const int lm   = lane & 15;
  const size_t rowtop = (size_t)blockIdx.x * RPB;

#define XLOAD(AV, c)                                                           \
  do {                                                                         \
    const float* xp_ = X + (rowtop + (size_t)(c) * CHUNK + wv * 16 + lm) * DDIM\
                         + lg * 8;                                             \
    _Pragma("unroll")                                                          \
    for (int kk = 0; kk < 8; ++kk){                                            \
      AV[2*kk]   = *reinterpret_cast<const f32x4*>(xp_ + kk * 32);             \
      AV[2*kk+1] = *reinterpret_cast<const f32x4*>(xp_ + kk * 32 + 4);         \
    }                                                                          \
  } while (0)

#define COMPUTE(AV, c)                                                         \
  do {                                                                         \
    f32x4 acc[16];                                                             \
    _Pragma("unroll")                                                          \
    for (int nt = 0; nt < 16; ++nt) acc[nt] = (f32x4){0.f, 0.f, 0.f, 0.f};     \
    _Pragma("unroll")                                                          \
    for (int kk = 0; kk < 8; ++kk){                                            \
      const f32x4 lo = AV[2*kk], hi = AV[2*kk+1];                              \
      short8 a;                                                                \
      a[0] = (short)f2bf(lo[0]); a[1] = (short)f2bf(lo[1]);                    \
      a[2] = (short)f2bf(lo[2]); a[3] = (short)f2bf(lo[3]);                    \
      a[4] = (short)f2bf(hi[0]); a[5] = (short)f2bf(hi[1]);                    \
      a[6] = (short)f2bf(hi[2]); a[7] = (short)f2bf(hi[3]);                    \
      const int kb = kk * 64 + (lg << 4);                                      \
      _Pragma("unroll")                                                        \
      for (int nt = 0; nt < 16; ++nt){                                         \
        const int n = nt * 16 + lm;                                            \
        const short8 bfr = *reinterpret_cast<const short8*>(                   \
            qb + (n << 9) + (kb ^ ((n & 7) << 4)));                            \
        acc[nt] = __builtin_amdgcn_mfma_f32_16x16x32_bf16(a, bfr, acc[nt],     \
                                                          0, 0, 0);            \
      }                                                                        \
    }                                                                          \
    const size_t orow_ = rowtop + (size_t)(c) * CHUNK + wv * 16 + lg * 4;      \
    _Pragma("unroll")                                                          \
    for (int nt = 0; nt < 16; ++nt){                                           \
      _Pragma("unroll")                                                        \
      for (int r = 0; r < 4; ++r){                                             \
        Y[(orow_ + r) * DDIM + nt * 16 + lm] = acc[nt][r];                     \
      }                                                                        \
    }                                                                          \
  } while (0)

  f32x4 avA[16], avB[16];
  XLOAD(avA, 0);                              // chunk-0 loads fly during stage

  // Stage Q^T -> LDS once. 8192 16B chunks, 16 per thread, coalesced.
#pragma unroll
  for (int it = 0; it < 16; ++it){
    const int c   = tid + it * 512;           // 0..8191
    const int n   = c >> 5;                   // row (n-dim)
    const int off = (c & 31) << 4;            // byte offset within row
    const f32x4 d = *reinterpret_cast<const f32x4*>(
        reinterpret_cast<const char*>(Qt) + (n << 9) + off);
    *reinterpret_cast<f32x4*>(qb + (n << 9) + (off ^ ((n & 7) << 4))) = d;
  }
  __syncthreads();

  XLOAD(avB, 1);
  COMPUTE(avA, 0);
  XLOAD(avA, 2);
  COMPUTE(avB, 1);
  XLOAD(avB, 3);
  COMPUTE(avA, 2);
  COMPUTE(avB, 3);

#undef XLOAD
#undef COMPUTE
}

extern "C" void kernel_launch(void* const* d_in, const int* in_sizes, int n_in,
                              void* d_out, int out_size, void* d_ws, size_t ws_size,
                              hipStream_t stream) {
  const float* X = (const float*)d_in[0];     // [131072, 256]
  const float* U = (const float*)d_in[1];     // [256, 256]
  float* Y = (float*)d_out;                   // [131072, 256]
  unsigned short* Qt = (unsigned short*)d_ws; // 256*256 bf16 = 128 KB scratch

  // beta lives in the tail of d_out: consumed by compute_q (stream-ordered)
  // before gemm_xq overwrites all of d_out.
  float* beta = (float*)d_out + ((size_t)out_size - 256);

  compute_beta<<<1, 256, 0, stream>>>(U, beta);
  compute_q<<<32, 256, 0, stream>>>(U, beta, Qt);
  gemm_xq<<<GBLK, 512, 0, stream>>>(X, Qt, Y);
}

// Round 5
// 104.981 us; speedup vs baseline: 1.4072x; 1.0715x over previous
//
#include <hip/hip_runtime.h>
#include <hip/hip_bf16.h>

typedef __attribute__((ext_vector_type(8))) short short8;
typedef __attribute__((ext_vector_type(4))) float f32x4;

#define DDIM 256
#define NROWS 131072
#define GBLK 512              // grid: 2 rounds over 256 CUs (load-balance slack)
#define RPB (NROWS / GBLK)    // 256 rows per block = 16 waves x 16 rows

static __device__ __forceinline__ unsigned short f2bf(float f){
  unsigned b = __builtin_bit_cast(unsigned, f);
  b += 0x7FFFu + ((b >> 16) & 1u);          // RNE round to bf16
  return (unsigned short)(b >> 16);
}

// Wave64 sum-reduction via DPP (VALU-only). row_shr 1/2/4/8 then
// row_bcast:15 / row_bcast:31 -> total in lane 63; readlane broadcasts.
static __device__ __forceinline__ float wave_sum_bcast(float x){
  int v = __builtin_bit_cast(int, x);
#define DPP_ADD(ctrl)                                                          \
  v = __builtin_bit_cast(int,                                                  \
        __builtin_bit_cast(float, v) +                                         \
        __builtin_bit_cast(float,                                              \
          __builtin_amdgcn_update_dpp(0, v, (ctrl), 0xF, 0xF, true)))
  DPP_ADD(0x111);  // row_shr:1
  DPP_ADD(0x112);  // row_shr:2
  DPP_ADD(0x114);  // row_shr:4
  DPP_ADD(0x118);  // row_shr:8
  DPP_ADD(0x142);  // row_bcast:15
  DPP_ADD(0x143);  // row_bcast:31
#undef DPP_ADD
  return __builtin_bit_cast(float, __builtin_amdgcn_readlane(v, 63));
}

// ---------------------------------------------------------------------------
// Kernel 0: beta[k] = 2 / ||U[k]||^2.
// ---------------------------------------------------------------------------
__global__ __launch_bounds__(256) void compute_beta(const float* __restrict__ U,
                                                    float* __restrict__ beta){
  const int k = threadIdx.x;
  const f32x4* r = reinterpret_cast<const f32x4*>(U + (size_t)k * 256);
  float s0 = 0.f, s1 = 0.f, s2 = 0.f, s3 = 0.f;
#pragma unroll
  for (int i = 0; i < 64; i += 4){
    f32x4 a = r[i], b = r[i + 1], c = r[i + 2], d = r[i + 3];
    s0 += a[0]*a[0] + a[1]*a[1] + a[2]*a[2] + a[3]*a[3];
    s1 += b[0]*b[0] + b[1]*b[1] + b[2]*b[2] + b[3]*b[3];
    s2 += c[0]*c[0] + c[1]*c[1] + c[2]*c[2] + c[3]*c[3];
    s3 += d[0]*d[0] + d[1]*d[1] + d[2]*d[2] + d[3]*d[3];
  }
  beta[k] = 2.0f / ((s0 + s1) + (s2 + s3));
}

// ---------------------------------------------------------------------------
// Kernel A: Q columns via 256 sequential Householder steps; 2 cols/wave.
// Depth-4 rotating prefetch of U rows + betas hides load latency under
// 4 x ~70cy DPP step bodies.  Writes Q^T (bf16) to Qt[n][k].
// ---------------------------------------------------------------------------
__global__ __launch_bounds__(256) void compute_q(const float* __restrict__ U,
                                                 const float* __restrict__ beta,
                                                 unsigned short* __restrict__ Qt){
  const int lane = threadIdx.x & 63;
  const int wv   = threadIdx.x >> 6;          // 0..3
  const int pair = blockIdx.x * 4 + wv;       // 0..127
  const int j0 = pair * 2, j1 = j0 + 1;

  float u0[4], u1[4], r0[4], r1[4], r2[4], r3[4];
#pragma unroll
  for (int e = 0; e < 4; ++e){
    const int i = e * 64 + lane;
    u0[e] = (i == j0) ? 1.f : 0.f;
    u1[e] = (i == j1) ? 1.f : 0.f;
    r0[e] = U[0 * 256 + i];
    r1[e] = U[1 * 256 + i];
    r2[e] = U[2 * 256 + i];
    r3[e] = U[3 * 256 + i];
  }
  float b0 = beta[0], b1 = beta[1], b2 = beta[2], b3 = beta[3];

#define QSTEP(R, B, KN)                                                        \
  do {                                                                         \
    const float p0_ = (u0[0]*R[0] + u0[1]*R[1]) + (u0[2]*R[2] + u0[3]*R[3]);   \
    const float p1_ = (u1[0]*R[0] + u1[1]*R[1]) + (u1[2]*R[2] + u1[3]*R[3]);   \
    const float d0_ = wave_sum_bcast(p0_);                                     \
    const float d1_ = wave_sum_bcast(p1_);                                     \
    const float c0_ = d0_ * B, c1_ = d1_ * B;                                  \
    _Pragma("unroll")                                                          \
    for (int e = 0; e < 4; ++e){                                               \
      u0[e] = fmaf(-c0_, R[e], u0[e]);                                         \
      u1[e] = fmaf(-c1_, R[e], u1[e]);                                         \
      R[e] = U[(size_t)(KN) * 256 + e * 64 + lane];                            \
    }                                                                          \
    B = beta[(KN)];                                                            \
  } while (0)

  for (int k = 0; k < 256; k += 4){
    const int k4 = (k+4) & 255, k5 = (k+5) & 255, k6 = (k+6) & 255, k7 = (k+7) & 255;
    QSTEP(r0, b0, k4);
    QSTEP(r1, b1, k5);
    QSTEP(r2, b2, k6);
    QSTEP(r3, b3, k7);
  }
#undef QSTEP

#pragma unroll
  for (int e = 0; e < 4; ++e){
    const int i = e * 64 + lane;
    Qt[(size_t)j0 * 256 + i] = f2bf(u0[e]);
    Qt[(size_t)j1 * 256 + i] = f2bf(u1[e]);
  }
}

// ---------------------------------------------------------------------------
// Kernel B: Y = X * Q.  512 blocks x 1024 threads (16 waves = 4/SIMD -> 50%
// occupancy ceiling).  Block owns 256 rows; Qt staged into LDS once with
// full-row XOR swizzle ((n&15)<<5): B-read slot = (kk*4+lg) ^ (lm<<1) ->
// exactly 2 lanes per 16B slot (different rows) -> conflict-free (m136).
// Per-wave regs <= 128 (4 waves/SIMD): xv fp32 (64, full 16-load MLP) +
// acc 8xf32x4 (32, two sequential N-halves; f2bf conversion redone per half).
// mfma_f32_16x16x32_bf16 layouts (m89/m97):
//   A: lane holds A[l&15][kk*32+8*(l>>4)+j]   B: same, n=l&15
//   D: D[(l>>4)*4+r][l&15]
// ---------------------------------------------------------------------------
__global__ __launch_bounds__(1024, 4) void gemm_xq(const float* __restrict__ X,
                                                   const unsigned short* __restrict__ Qt,
                                                   float* __restrict__ Y){
  __shared__ char qb[131072];                 // 256 rows (n) x 512 B (k, bf16)

  const int tid  = threadIdx.x;
  const int lane = tid & 63;
  const int wv   = tid >> 6;                  // 0..15
  const int lg   = lane >> 4;                 // 0..3
  const int lm   = lane & 15;
  const size_t row0 = (size_t)blockIdx.x * RPB + wv * 16;

  // Issue all 16 X row-loads first; latency hides under Qt staging + barrier.
  const float* xp = X + (row0 + lm) * DDIM + lg * 8;
  f32x4 xv[16];
#pragma unroll
  for (int kk = 0; kk < 8; ++kk){
    xv[2*kk]   = *reinterpret_cast<const f32x4*>(xp + kk * 32);
    xv[2*kk+1] = *reinterpret_cast<const f32x4*>(xp + kk * 32 + 4);
  }

  // Stage Q^T -> LDS. 8192 16B chunks, 8 per thread, coalesced reads.
  // Write-side: 2 rows per wave x 32 distinct slots -> conflict-free.
#pragma unroll
  for (int it = 0; it < 8; ++it){
    const int c   = tid + it * 1024;          // 0..8191
    const int n   = c >> 5;                   // row (n-dim)
    const int off = (c & 31) << 4;            // byte offset within row
    const f32x4 d = *reinterpret_cast<const f32x4*>(
        reinterpret_cast<const char*>(Qt) + (n << 9) + off);
    *reinterpret_cast<f32x4*>(qb + (n << 9) + (off ^ ((n & 15) << 5))) = d;
  }
  __syncthreads();

#pragma unroll
  for (int h = 0; h < 2; ++h){                // two 128-col halves
    f32x4 acc[8];
#pragma unroll
    for (int nt = 0; nt < 8; ++nt) acc[nt] = (f32x4){0.f, 0.f, 0.f, 0.f};

#pragma unroll
    for (int kk = 0; kk < 8; ++kk){
      const f32x4 lo = xv[2*kk], hi = xv[2*kk+1];
      short8 a;
      a[0] = (short)f2bf(lo[0]); a[1] = (short)f2bf(lo[1]);
      a[2] = (short)f2bf(lo[2]); a[3] = (short)f2bf(lo[3]);
      a[4] = (short)f2bf(hi[0]); a[5] = (short)f2bf(hi[1]);
      a[6] = (short)f2bf(hi[2]); a[7] = (short)f2bf(hi[3]);

      const int kb = kk * 64 + (lg << 4);     // byte offset of lane's 8 bf16 in k
#pragma unroll
      for (int nt = 0; nt < 8; ++nt){
        const int n = h * 128 + nt * 16 + lm;
        const short8 b = *reinterpret_cast<const short8*>(
            qb + (n << 9) + (kb ^ ((n & 15) << 5)));
        acc[nt] = __builtin_amdgcn_mfma_f32_16x16x32_bf16(a, b, acc[nt], 0, 0, 0);
      }
    }

    // Epilogue: D[(l>>4)*4+r][l&15] per 16x16 tile.
    const size_t orow = row0 + lg * 4;
#pragma unroll
    for (int nt = 0; nt < 8; ++nt){
#pragma unroll
      for (int r = 0; r < 4; ++r){
        Y[(orow + r) * DDIM + h * 128 + nt * 16 + lm] = acc[nt][r];
      }
    }
  }
}

extern "C" void kernel_launch(void* const* d_in, const int* in_sizes, int n_in,
                              void* d_out, int out_size, void* d_ws, size_t ws_size,
                              hipStream_t stream) {
  const float* X = (const float*)d_in[0];     // [131072, 256]
  const float* U = (const float*)d_in[1];     // [256, 256]
  float* Y = (float*)d_out;                   // [131072, 256]
  unsigned short* Qt = (unsigned short*)d_ws; // 256*256 bf16 = 128 KB scratch

  // beta lives in the tail of d_out: consumed by compute_q (stream-ordered)
  // before gemm_xq overwrites all of d_out.
  float* beta = (float*)d_out + ((size_t)out_size - 256);

  compute_beta<<<1, 256, 0, stream>>>(U, beta);
  compute_q<<<32, 256, 0, stream>>>(U, beta, Qt);
  gemm_xq<<<GBLK, 1024, 0, stream>>>(X, Qt, Y);
}